// Round 4
// baseline (49.747 us; speedup 1.0000x reference)
//
#include <hip/hip_runtime.h>

// Input: (2, 1, 256, 256, 256) float32. x = inputs[:,0] -> (2,256,256,256).
// dd = (core - x[d+1]) * 256 ; dh = (core - x[h+1]) * 256 ; dw = (core - x[w+1]) * 256
// out = mean(|sqrt(dd^2+dh^2+dw^2) - 1|) over 2*255^3 core elements.
//
// Fused single-kernel version: 4-row register pencil per wave (16-plane
// d-chunks, 512 blocks = 2 blocks/CU), last-block-done final reduction
// (deterministic: fixed partial slots, fixed-order double tree).

#define DVOL 256
#define PLANE (DVOL * DVOL)
#define CORE 255
#define DCH 16
#define NBLK 512  // 2 b * 16 dchunks * 16 hgroups

__device__ __forceinline__ float sq(float v) { return v * v; }

__device__ __forceinline__ float row_term(const float4 c, const float4 h1,
                                          const float4 d1, int lane, bool valid) {
    const float nx = __shfl_down(c.x, 1, 64);  // lane+1's first element (all lanes participate)
    if (!valid) return 0.0f;
    float acc;
    float s;
    s = sq(c.x - d1.x) + sq(c.x - h1.x) + sq(c.x - c.y);
    acc = fabsf(fmaf(256.0f, sqrtf(s), -1.0f));
    s = sq(c.y - d1.y) + sq(c.y - h1.y) + sq(c.y - c.z);
    acc += fabsf(fmaf(256.0f, sqrtf(s), -1.0f));
    s = sq(c.z - d1.z) + sq(c.z - h1.z) + sq(c.z - c.w);
    acc += fabsf(fmaf(256.0f, sqrtf(s), -1.0f));
    if (lane != 63) {  // w = lane*4+3 = 255 is not core
        s = sq(c.w - d1.w) + sq(c.w - h1.w) + sq(c.w - nx);
        acc += fabsf(fmaf(256.0f, sqrtf(s), -1.0f));
    }
    return acc;
}

__global__ __launch_bounds__(256) void eik_fused(const float* __restrict__ x,
                                                 float* __restrict__ part,
                                                 unsigned int* __restrict__ counter,
                                                 float* __restrict__ out) {
    const int tid  = threadIdx.x;
    const int lane = tid & 63;
    const int wave = tid >> 6;

    const int blk = blockIdx.x;             // [0, 512)
    const int b   = blk >> 8;               // batch
    const int dc  = (blk >> 4) & 15;        // d-chunk (16 planes)
    const int hg  = (blk & 15) * 4 + wave;  // h-group [0,64), 4 rows each
    const int h   = hg * 4;                 // first row: 0..252
    const int d0  = dc * DCH;
    const int dend = min(d0 + DCH, CORE);   // last chunk: 15 planes
    const bool row3_valid = (h + 3 < CORE); // hg=63: row 255 not core
    const int ch_off = (h + 4 < DVOL) ? 4 * DVOL : 3 * DVOL;  // clamped, unused when invalid

    const float* base = x + (long long)b * (DVOL * PLANE)
                          + (long long)d0 * PLANE
                          + (long long)h * DVOL
                          + lane * 4;

    float4 r0 = *(const float4*)(base);
    float4 r1 = *(const float4*)(base + DVOL);
    float4 r2 = *(const float4*)(base + 2 * DVOL);
    float4 r3 = *(const float4*)(base + 3 * DVOL);

    float acc = 0.0f;
    for (int d = d0; d < dend; ++d) {
        const float4 cd0 = *(const float4*)(base + PLANE);
        const float4 cd1 = *(const float4*)(base + PLANE + DVOL);
        const float4 cd2 = *(const float4*)(base + PLANE + 2 * DVOL);
        const float4 cd3 = *(const float4*)(base + PLANE + 3 * DVOL);
        const float4 ch  = *(const float4*)(base + ch_off);  // row h+4, plane d (L1/L2 hit)

        acc += row_term(r0, r1, cd0, lane, true);
        acc += row_term(r1, r2, cd1, lane, true);
        acc += row_term(r2, r3, cd2, lane, true);
        acc += row_term(r3, ch, cd3, lane, row3_valid);

        r0 = cd0; r1 = cd1; r2 = cd2; r3 = cd3;
        base += PLANE;
    }

    // wave shuffle reduction
    #pragma unroll
    for (int off = 32; off > 0; off >>= 1)
        acc += __shfl_down(acc, off, 64);

    __shared__ float wsum[4];
    __shared__ bool isLast;
    if (lane == 0) wsum[wave] = acc;
    __syncthreads();
    if (tid == 0) {
        part[blk] = wsum[0] + wsum[1] + wsum[2] + wsum[3];
        __threadfence();  // make partial visible device-wide before signaling
        unsigned int old = atomicAdd(counter, 1u);
        isLast = (old == NBLK - 1);
    }
    __syncthreads();
    if (!isLast) return;

    // last block: deterministic fixed-order double reduction of 512 partials
    __threadfence();
    double s = (double)part[tid] + (double)part[tid + 256];
    __shared__ double sm[256];
    sm[tid] = s;
    __syncthreads();
    #pragma unroll
    for (int off = 128; off > 0; off >>= 1) {
        if (tid < off) sm[tid] += sm[tid + off];
        __syncthreads();
    }
    if (tid == 0) {
        const double N = 2.0 * CORE * CORE * CORE;  // 33,162,750
        out[0] = (float)(sm[0] / N);
    }
}

extern "C" void kernel_launch(void* const* d_in, const int* in_sizes, int n_in,
                              void* d_out, int out_size, void* d_ws, size_t ws_size,
                              hipStream_t stream) {
    const float* x = (const float*)d_in[0];
    float* out = (float*)d_out;
    float* part = (float*)d_ws;                                        // 512 floats
    unsigned int* counter = (unsigned int*)((char*)d_ws + 512 * sizeof(float));

    hipMemsetAsync(counter, 0, sizeof(unsigned int), stream);
    eik_fused<<<NBLK, 256, 0, stream>>>(x, part, counter, out);
}